// Round 4
// baseline (3465.325 us; speedup 1.0000x reference)
//
#include <hip/hip_runtime.h>
#include <stdint.h>
#include <stddef.h>

#define B_ 256
#define L_ 151
#define D_ 256
#define H_ 8
#define DH_ 32
#define FF_ 2048
#define NL_ 6
#define M_ (B_ * L_)      // 38656 = 302 * 128

typedef unsigned short ushort_t;
typedef __bf16 bf16x8 __attribute__((ext_vector_type(8)));
typedef float f32x4 __attribute__((ext_vector_type(4)));

__device__ __forceinline__ float bf2f(ushort_t u) {
    union { unsigned int i; float f; } v;
    v.i = ((unsigned int)u) << 16;
    return v.f;
}
__device__ __forceinline__ ushort_t f2bf(float f) {
    union { float f; unsigned int i; } v;
    v.f = f;
    unsigned int x = v.i;
    return (ushort_t)((x + 0x7fffu + ((x >> 16) & 1u)) >> 16);
}

__device__ __forceinline__ void gld_lds16(const ushort_t* g, ushort_t* l) {
    __builtin_amdgcn_global_load_lds(
        (const __attribute__((address_space(1))) void*)g,
        (__attribute__((address_space(3))) void*)l,
        16, 0, 0);
}

// ---------------------------------------------------------------------------
// Input dtype detection. For bf16 data, word = elem(2i) | elem(2i+1)<<16; the
// low half is a bf16 of ~N(0,1)-scale data -> exponent (w>>7)&0xFF in
// [110,140] essentially always. For fp32 data the low half is random mantissa
// bits -> ~12% in-window. Majority over 1024 words is decisive.
// flag: 0 = bf16 inputs, 1 = fp32 inputs.
// ---------------------------------------------------------------------------
__global__ __launch_bounds__(256)
void detect_kernel(const unsigned int* __restrict__ w, int* __restrict__ flag)
{
    __shared__ int sh[256];
    int tid = threadIdx.x;
    int cnt = 0;
    for (int i = tid; i < 1024; i += 256) {
        unsigned int x = w[i];
        int e = (x >> 7) & 0xFF;
        cnt += (e >= 110 && e <= 140) ? 1 : 0;
    }
    sh[tid] = cnt;
    __syncthreads();
    for (int s = 128; s > 0; s >>= 1) {
        if (tid < s) sh[tid] += sh[tid + s];
        __syncthreads();
    }
    if (tid == 0) *flag = (sh[0] > 512) ? 0 : 1;
}

// Convert one array (n elements, n % 256 == 0) to bf16 per flag.
__global__ __launch_bounds__(256)
void cvt_w_kernel(const void* __restrict__ in, const int* __restrict__ flag,
                  ushort_t* __restrict__ out)
{
    size_t i = (size_t)blockIdx.x * 256 + threadIdx.x;
    if (*flag) out[i] = f2bf(((const float*)in)[i]);
    else       out[i] = ((const ushort_t*)in)[i];
}

// src -> fp32 residual stream + bf16 GEMM copy.
__global__ __launch_bounds__(256)
void cvt_src_kernel(const void* __restrict__ in, const int* __restrict__ flag,
                    float* __restrict__ xf, ushort_t* __restrict__ xb)
{
    size_t i = (size_t)blockIdx.x * 256 + threadIdx.x;
    float v = (*flag) ? ((const float*)in)[i] : bf2f(((const ushort_t*)in)[i]);
    xf[i] = v;
    xb[i] = f2bf(v);
}

// ---------------------------------------------------------------------------
// GEMM: Out[M,N] = A[M,K] * Bw[N,K]^T + bias, optional relu, bf16 out.
// A row stride = lda (elements). 128x128 tile, 4 waves, BK=64,
// global_load_lds width-16 staging (m97 structure).
// ---------------------------------------------------------------------------
__global__ __launch_bounds__(256, 2)
void gemm_bt(const ushort_t* __restrict__ A, const ushort_t* __restrict__ Bw,
             const ushort_t* __restrict__ bias, ushort_t* __restrict__ Out,
             int N, int K, int lda, int relu)
{
    alignas(16) __shared__ ushort_t lsA[128 * 64];
    alignas(16) __shared__ ushort_t lsB[128 * 64];

    const int tid  = threadIdx.x;
    const int wave = tid >> 6;
    const int lane = tid & 63;
    const int row0 = blockIdx.y * 128;
    const int col0 = blockIdx.x * 128;

    const int wr   = (wave >> 1) * 64;
    const int wc   = (wave & 1) * 64;
    const int lm   = lane & 15;
    const int quad = lane >> 4;

    f32x4 acc[4][4];
#pragma unroll
    for (int i = 0; i < 4; ++i)
#pragma unroll
        for (int j = 0; j < 4; ++j)
            acc[i][j] = (f32x4){0.f, 0.f, 0.f, 0.f};

    for (int k0 = 0; k0 < K; k0 += 64) {
        __syncthreads();   // all waves done reading previous tile
#pragma unroll
        for (int it = 0; it < 4; ++it) {
            int c16 = (it * 4 + wave) * 64 + lane;    // 16B chunk index
            int r   = c16 >> 3;
            int kc  = c16 & 7;
            const ushort_t* ga = A  + (size_t)(row0 + r) * lda + k0 + kc * 8;
            const ushort_t* gb = Bw + (size_t)(col0 + r) * K   + k0 + kc * 8;
            ushort_t* la = &lsA[(size_t)(it * 4 + wave) * 512];  // wave-uniform base
            ushort_t* lb = &lsB[(size_t)(it * 4 + wave) * 512];
            gld_lds16(ga, la);
            gld_lds16(gb, lb);
        }
        __syncthreads();   // staging complete

#pragma unroll
        for (int kc = 0; kc < 2; ++kc) {
            bf16x8 af[4], bfr[4];
#pragma unroll
            for (int i = 0; i < 4; ++i) {
                af[i]  = *reinterpret_cast<const bf16x8*>(
                             &lsA[(wr + i * 16 + lm) * 64 + kc * 32 + quad * 8]);
                bfr[i] = *reinterpret_cast<const bf16x8*>(
                             &lsB[(wc + i * 16 + lm) * 64 + kc * 32 + quad * 8]);
            }
#pragma unroll
            for (int i = 0; i < 4; ++i)
#pragma unroll
                for (int j = 0; j < 4; ++j)
                    acc[i][j] = __builtin_amdgcn_mfma_f32_16x16x32_bf16(
                        af[i], bfr[j], acc[i][j], 0, 0, 0);
        }
    }

    // epilogue: C[m = quad*4+r][n = lane&15] per 16x16 tile
    float bvals[4];
#pragma unroll
    for (int j = 0; j < 4; ++j)
        bvals[j] = bf2f(bias[col0 + wc + j * 16 + lm]);

#pragma unroll
    for (int i = 0; i < 4; ++i) {
        int mrow = row0 + wr + i * 16 + quad * 4;
#pragma unroll
        for (int j = 0; j < 4; ++j) {
            int ncol = col0 + wc + j * 16 + lm;
#pragma unroll
            for (int r = 0; r < 4; ++r) {
                float v = acc[i][j][r] + bvals[j];
                if (relu) v = fmaxf(v, 0.f);
                Out[(size_t)(mrow + r) * N + ncol] = f2bf(v);
            }
        }
    }
}

// ---------------------------------------------------------------------------
// Block-diagonal attention. One workgroup per (batch, seq-block), loop heads.
// qkv: [M, 768] bf16 (q|k|v each 256 = 8 heads x 32). ctx overwrites the q
// columns in-place (head h's q is consumed into LDS before its ctx write;
// later heads use disjoint columns). Block-local softmax == full softmax with
// the -1e9 mask (masked exp underflows to exactly 0 in fp32).
// ---------------------------------------------------------------------------
__constant__ int c_starts[6] = {0, 50, 67, 84, 101, 151};

__global__ __launch_bounds__(256)
void attn_kernel(ushort_t* __restrict__ qkv)
{
    __shared__ float qs[50][33];
    __shared__ float ks[50][33];
    __shared__ float vs[50][33];
    __shared__ float es[50][51];
    __shared__ float inv[50];

    const int b   = blockIdx.x / 5;
    const int blk = blockIdx.x % 5;
    const int a0  = c_starts[blk];
    const int n   = c_starts[blk + 1] - a0;
    const int tid = threadIdx.x;
    const float scale = 0.17677669529663687f;  // 1/sqrt(32)

    for (int h = 0; h < H_; ++h) {
        __syncthreads();  // LDS reuse guard between heads
        for (int idx = tid; idx < n * 32; idx += 256) {
            int r = idx >> 5, d = idx & 31;
            size_t base = ((size_t)(b * L_ + a0 + r)) * 768 + h * 32 + d;
            qs[r][d] = bf2f(qkv[base]);
            ks[r][d] = bf2f(qkv[base + 256]);
            vs[r][d] = bf2f(qkv[base + 512]);
        }
        __syncthreads();

        for (int e = tid; e < n * n; e += 256) {
            int r = e / n, c = e - r * n;
            float acc = 0.f;
#pragma unroll
            for (int d = 0; d < 32; ++d) acc += qs[r][d] * ks[c][d];
            es[r][c] = acc * scale;
        }
        __syncthreads();

        if (tid < n) {
            int r = tid;
            float mx = -1e30f;
            for (int c = 0; c < n; ++c) mx = fmaxf(mx, es[r][c]);
            float sm = 0.f;
            for (int c = 0; c < n; ++c) {
                float e2 = __expf(es[r][c] - mx);
                es[r][c] = e2;
                sm += e2;
            }
            inv[r] = 1.0f / sm;
        }
        __syncthreads();

        for (int idx = tid; idx < n * 32; idx += 256) {
            int r = idx >> 5, d = idx & 31;
            float acc = 0.f;
            for (int c = 0; c < n; ++c) acc += es[r][c] * vs[c][d];
            size_t o = ((size_t)(b * L_ + a0 + r)) * 768 + h * 32 + d;  // q slot
            qkv[o] = f2bf(acc * inv[r]);
        }
    }
}

// ---------------------------------------------------------------------------
// Residual + LayerNorm: y = LN(xin + delta)*s + b. One wave per row (D=256).
// Always refreshes the fp32 residual stream. Non-final (or bf16 dataset):
// bf16 copy -> xb_out. Final layer on fp32 dataset: fp32 -> f32_dst (d_out).
// ---------------------------------------------------------------------------
__global__ __launch_bounds__(256)
void ln_kernel(const float* __restrict__ xin, const ushort_t* __restrict__ delta,
               const ushort_t* __restrict__ s, const ushort_t* __restrict__ b,
               float* __restrict__ xf_out, ushort_t* __restrict__ xb_out,
               float* __restrict__ f32_dst, const int* __restrict__ flag,
               int is_final)
{
    const int wave = threadIdx.x >> 6;
    const int lane = threadIdx.x & 63;
    const int row  = blockIdx.x * 4 + wave;
    const size_t off = (size_t)row * D_ + lane * 4;

    float4 xv = *(const float4*)(xin + off);
    ushort4 du = *(const ushort4*)(delta + off);
    float v0 = xv.x + bf2f(du.x), v1 = xv.y + bf2f(du.y);
    float v2 = xv.z + bf2f(du.z), v3 = xv.w + bf2f(du.w);

    float sum = v0 + v1 + v2 + v3;
#pragma unroll
    for (int o2 = 32; o2 > 0; o2 >>= 1) sum += __shfl_xor(sum, o2, 64);
    float mu = sum * (1.f / 256.f);

    float d0 = v0 - mu, d1 = v1 - mu, d2 = v2 - mu, d3 = v3 - mu;
    float ss = d0 * d0 + d1 * d1 + d2 * d2 + d3 * d3;
#pragma unroll
    for (int o2 = 32; o2 > 0; o2 >>= 1) ss += __shfl_xor(ss, o2, 64);
    float rstd = rsqrtf(ss * (1.f / 256.f) + 1e-5f);

    int c = lane * 4;
    float y0 = d0 * rstd * bf2f(s[c + 0]) + bf2f(b[c + 0]);
    float y1 = d1 * rstd * bf2f(s[c + 1]) + bf2f(b[c + 1]);
    float y2 = d2 * rstd * bf2f(s[c + 2]) + bf2f(b[c + 2]);
    float y3 = d3 * rstd * bf2f(s[c + 3]) + bf2f(b[c + 3]);

    *(float4*)(xf_out + off) = make_float4(y0, y1, y2, y3);
    if (is_final && *flag) {
        *(float4*)(f32_dst + off) = make_float4(y0, y1, y2, y3);
    } else {
        ushort4 uv;
        uv.x = f2bf(y0); uv.y = f2bf(y1); uv.z = f2bf(y2); uv.w = f2bf(y3);
        *(ushort4*)(xb_out + off) = uv;
    }
}

// ---------------------------------------------------------------------------
// Workspace: x_f32 39.58MB | U 59.38MB | tmp 19.79MB | Wbf 15.78MB | flag
// total ~134.6MB. bf16 residual copy x_b lives at d_out start (scratch);
// the final LN overwrites d_out with the real answer in the right dtype.
// ---------------------------------------------------------------------------
extern "C" void kernel_launch(void* const* d_in, const int* in_sizes, int n_in,
                              void* d_out, int out_size, void* d_ws, size_t ws_size,
                              hipStream_t stream)
{
    char* ws = (char*)d_ws;
    size_t o = 0;
    float*    x_f32 = (float*)(ws + o);    o += (size_t)M_ * D_ * 4;
    ushort_t* U     = (ushort_t*)(ws + o); o += (size_t)M_ * 768 * 2;
    ushort_t* tmp   = (ushort_t*)(ws + o); o += (size_t)M_ * D_ * 2;
    ushort_t* Wbf   = (ushort_t*)(ws + o); o += (size_t)7890432 * 2;
    int*      flag  = (int*)(ws + o);      o += 256;
    ushort_t* x_b   = (ushort_t*)d_out;    // bf16 residual copy (scratch)
    (void)ws_size; (void)in_sizes; (void)n_in; (void)out_size;

    // dtype detection + conversions
    detect_kernel<<<1, 256, 0, stream>>>((const unsigned int*)d_in[0], flag);

    // converted-weight layout inside Wbf (element offsets)
    const size_t n_arr[12] = {
        (size_t)NL_ * 768 * D_,  (size_t)NL_ * 768,        // qkv_w, qkv_b
        (size_t)NL_ * D_ * D_,   (size_t)NL_ * D_,         // out_w, out_b
        (size_t)NL_ * FF_ * D_,  (size_t)NL_ * FF_,        // ff1_w, ff1_b
        (size_t)NL_ * D_ * FF_,  (size_t)NL_ * D_,         // ff2_w, ff2_b
        (size_t)NL_ * D_, (size_t)NL_ * D_,                // ln1_s, ln1_b
        (size_t)NL_ * D_, (size_t)NL_ * D_                 // ln2_s, ln2_b
    };
    ushort_t* wptr[12];
    {
        size_t woff = 0;
        for (int a = 0; a < 12; ++a) {
            wptr[a] = Wbf + woff;
            woff += n_arr[a];
            cvt_w_kernel<<<(unsigned)(n_arr[a] / 256), 256, 0, stream>>>(
                d_in[a + 1], flag, wptr[a]);
        }
    }
    const ushort_t *qkv_w = wptr[0], *qkv_b = wptr[1], *out_w = wptr[2],
                   *out_b = wptr[3], *ff1_w = wptr[4], *ff1_b = wptr[5],
                   *ff2_w = wptr[6], *ff2_b = wptr[7], *ln1_s = wptr[8],
                   *ln1_b = wptr[9], *ln2_s = wptr[10], *ln2_b = wptr[11];

    cvt_src_kernel<<<(M_ * D_) / 256, 256, 0, stream>>>(d_in[0], flag, x_f32, x_b);

    const int chunk_tiles[4] = {76, 76, 75, 75};   // 302 M-tiles total

    for (int i = 0; i < NL_; ++i) {
        // QKV projection -> U [M,768] bf16
        gemm_bt<<<dim3(6, M_ / 128), 256, 0, stream>>>(
            x_b, qkv_w + (size_t)i * 768 * D_, qkv_b + (size_t)i * 768, U,
            768, D_, D_, 0);
        // block-diagonal attention; ctx overwrites q columns of U (stride 768)
        attn_kernel<<<B_ * 5, 256, 0, stream>>>(U);
        // out projection: A = ctx (U cols [0,256), lda=768) -> tmp bf16
        gemm_bt<<<dim3(2, M_ / 128), 256, 0, stream>>>(
            U, out_w + (size_t)i * D_ * D_, out_b + (size_t)i * D_, tmp,
            256, D_, 768, 0);
        // x = LN1(x + attn_out)
        ln_kernel<<<M_ / 4, 256, 0, stream>>>(
            x_f32, tmp, ln1_s + (size_t)i * D_, ln1_b + (size_t)i * D_,
            x_f32, x_b, nullptr, flag, 0);
        // FF in 4 M-chunks through U (h chunk = [<=9728, 2048] bf16)
        int t0 = 0;
        for (int c = 0; c < 4; ++c) {
            const int t = chunk_tiles[c];
            const size_t r0 = (size_t)t0 * 128;
            gemm_bt<<<dim3(16, t), 256, 0, stream>>>(
                x_b + r0 * D_, ff1_w + (size_t)i * FF_ * D_,
                ff1_b + (size_t)i * FF_, U, FF_, D_, D_, 1);
            gemm_bt<<<dim3(2, t), 256, 0, stream>>>(
                U, ff2_w + (size_t)i * D_ * FF_, ff2_b + (size_t)i * D_,
                tmp + r0 * D_, D_, FF_, FF_, 0);
            t0 += t;
        }
        // x = LN2(x + ff_out); final layer writes d_out in the right dtype
        ln_kernel<<<M_ / 4, 256, 0, stream>>>(
            x_f32, tmp, ln2_s + (size_t)i * D_, ln2_b + (size_t)i * D_,
            x_f32, x_b, (float*)d_out, flag, (i == NL_ - 1) ? 1 : 0);
    }
}

// Round 5
// 2945.817 us; speedup vs baseline: 1.1764x; 1.1764x over previous
//
#include <hip/hip_runtime.h>
#include <stdint.h>
#include <stddef.h>

#define B_ 256
#define L_ 151
#define D_ 256
#define H_ 8
#define DH_ 32
#define FF_ 2048
#define NL_ 6
#define M_ (B_ * L_)      // 38656 = 302 * 128

typedef unsigned short ushort_t;
typedef __bf16 bf16x8 __attribute__((ext_vector_type(8)));
typedef float f32x4 __attribute__((ext_vector_type(4)));
typedef unsigned short us8 __attribute__((ext_vector_type(8)));

__device__ __forceinline__ float bf2f(ushort_t u) {
    union { unsigned int i; float f; } v;
    v.i = ((unsigned int)u) << 16;
    return v.f;
}
__device__ __forceinline__ ushort_t f2bf(float f) {
    union { float f; unsigned int i; } v;
    v.f = f;
    unsigned int x = v.i;
    return (ushort_t)((x + 0x7fffu + ((x >> 16) & 1u)) >> 16);
}

__device__ __forceinline__ void gld_lds16(const ushort_t* g, ushort_t* l) {
    __builtin_amdgcn_global_load_lds(
        (const __attribute__((address_space(1))) void*)g,
        (__attribute__((address_space(3))) void*)l,
        16, 0, 0);
}

// ---------------------------------------------------------------------------
// Input dtype detection (flag: 0 = bf16 inputs, 1 = fp32 inputs).
// ---------------------------------------------------------------------------
__global__ __launch_bounds__(256)
void detect_kernel(const unsigned int* __restrict__ w, int* __restrict__ flag)
{
    __shared__ int sh[256];
    int tid = threadIdx.x;
    int cnt = 0;
    for (int i = tid; i < 1024; i += 256) {
        unsigned int x = w[i];
        int e = (x >> 7) & 0xFF;
        cnt += (e >= 110 && e <= 140) ? 1 : 0;
    }
    sh[tid] = cnt;
    __syncthreads();
    for (int s = 128; s > 0; s >>= 1) {
        if (tid < s) sh[tid] += sh[tid + s];
        __syncthreads();
    }
    if (tid == 0) *flag = (sh[0] > 512) ? 0 : 1;
}

// ---------------------------------------------------------------------------
// Convert ALL weights/biases to bf16 in one launch. Compile-time segment map
// (element offsets within the packed Wbf buffer == cumulative input sizes).
// ---------------------------------------------------------------------------
struct WPtrs { const void* p[12]; };

#define WTOT 7890432

__global__ __launch_bounds__(256)
void cvt_all_kernel(WPtrs w, const int* __restrict__ flag, ushort_t* __restrict__ out)
{
    size_t i = (size_t)blockIdx.x * 256 + threadIdx.x;
    if (i >= WTOT) return;
    int a; size_t base;
    if      (i < 1179648) { a = 0;  base = 0; }
    else if (i < 1184256) { a = 1;  base = 1179648; }
    else if (i < 1577472) { a = 2;  base = 1184256; }
    else if (i < 1579008) { a = 3;  base = 1577472; }
    else if (i < 4724736) { a = 4;  base = 1579008; }
    else if (i < 4737024) { a = 5;  base = 4724736; }
    else if (i < 7882752) { a = 6;  base = 4737024; }
    else if (i < 7884288) { a = 7;  base = 7882752; }
    else if (i < 7885824) { a = 8;  base = 7884288; }
    else if (i < 7887360) { a = 9;  base = 7885824; }
    else if (i < 7888896) { a = 10; base = 7887360; }
    else                  { a = 11; base = 7888896; }
    size_t j = i - base;
    if (*flag) out[i] = f2bf(((const float*)w.p[a])[j]);
    else       out[i] = ((const ushort_t*)w.p[a])[j];
}

// src -> fp32 residual stream + bf16 GEMM copy.
__global__ __launch_bounds__(256)
void cvt_src_kernel(const void* __restrict__ in, const int* __restrict__ flag,
                    float* __restrict__ xf, ushort_t* __restrict__ xb)
{
    size_t i = (size_t)blockIdx.x * 256 + threadIdx.x;
    float v = (*flag) ? ((const float*)in)[i] : bf2f(((const ushort_t*)in)[i]);
    xf[i] = v;
    xb[i] = f2bf(v);
}

// ---------------------------------------------------------------------------
// GEMM: 128x128 tile, 4 waves, BK=64, global_load_lds staging (m97).
// mode 0: Out=bf16 store; mode 1: bf16 store + relu; mode 2: fp32 Out[i] += v
// (residual fusion — each output element owned by exactly one thread).
// ---------------------------------------------------------------------------
__global__ __launch_bounds__(256, 2)
void gemm_bt(const ushort_t* __restrict__ A, const ushort_t* __restrict__ Bw,
             const ushort_t* __restrict__ bias, void* __restrict__ Out,
             int N, int K, int lda, int mode)
{
    alignas(16) __shared__ ushort_t lsA[128 * 64];
    alignas(16) __shared__ ushort_t lsB[128 * 64];

    const int tid  = threadIdx.x;
    const int wave = tid >> 6;
    const int lane = tid & 63;
    const int row0 = blockIdx.y * 128;
    const int col0 = blockIdx.x * 128;

    const int wr   = (wave >> 1) * 64;
    const int wc   = (wave & 1) * 64;
    const int lm   = lane & 15;
    const int quad = lane >> 4;

    f32x4 acc[4][4];
#pragma unroll
    for (int i = 0; i < 4; ++i)
#pragma unroll
        for (int j = 0; j < 4; ++j)
            acc[i][j] = (f32x4){0.f, 0.f, 0.f, 0.f};

    for (int k0 = 0; k0 < K; k0 += 64) {
        __syncthreads();
#pragma unroll
        for (int it = 0; it < 4; ++it) {
            int c16 = (it * 4 + wave) * 64 + lane;
            int r   = c16 >> 3;
            int kc  = c16 & 7;
            const ushort_t* ga = A  + (size_t)(row0 + r) * lda + k0 + kc * 8;
            const ushort_t* gb = Bw + (size_t)(col0 + r) * K   + k0 + kc * 8;
            gld_lds16(ga, &lsA[(size_t)(it * 4 + wave) * 512]);
            gld_lds16(gb, &lsB[(size_t)(it * 4 + wave) * 512]);
        }
        __syncthreads();

#pragma unroll
        for (int kc = 0; kc < 2; ++kc) {
            bf16x8 af[4], bfr[4];
#pragma unroll
            for (int i = 0; i < 4; ++i) {
                af[i]  = *reinterpret_cast<const bf16x8*>(
                             &lsA[(wr + i * 16 + lm) * 64 + kc * 32 + quad * 8]);
                bfr[i] = *reinterpret_cast<const bf16x8*>(
                             &lsB[(wc + i * 16 + lm) * 64 + kc * 32 + quad * 8]);
            }
#pragma unroll
            for (int i = 0; i < 4; ++i)
#pragma unroll
                for (int j = 0; j < 4; ++j)
                    acc[i][j] = __builtin_amdgcn_mfma_f32_16x16x32_bf16(
                        af[i], bfr[j], acc[i][j], 0, 0, 0);
        }
    }

    float bvals[4];
#pragma unroll
    for (int j = 0; j < 4; ++j)
        bvals[j] = bf2f(bias[col0 + wc + j * 16 + lm]);

#pragma unroll
    for (int i = 0; i < 4; ++i) {
        int mrow = row0 + wr + i * 16 + quad * 4;
#pragma unroll
        for (int j = 0; j < 4; ++j) {
            int ncol = col0 + wc + j * 16 + lm;
#pragma unroll
            for (int r = 0; r < 4; ++r) {
                float v = acc[i][j][r] + bvals[j];
                size_t idx = (size_t)(mrow + r) * N + ncol;
                if (mode == 2) {
                    ((float*)Out)[idx] += v;
                } else {
                    if (mode == 1) v = fmaxf(v, 0.f);
                    ((ushort_t*)Out)[idx] = f2bf(v);
                }
            }
        }
    }
}

// ---------------------------------------------------------------------------
// MFMA block-diagonal attention, wave-per-head, ZERO block barriers.
// Grid: 1280 = 256 batches x 5 seq-blocks; 4 waves; wave w does heads w, w+4.
// qkv: [M,768] bf16 (q|k|v). ctx overwrites q columns in-place (each wave
// writes only its own head's 32 columns; Q reads for later heads are disjoint
// or same-wave-ordered). Block-local softmax == masked softmax exactly.
// Layouts (verified vs gemm_bt): A-frag = X[m=lm][k=quad*8+j] (16B global or
// LDS b128); B-frag = Y[n=lm][k=quad*8+j]; C/D: row=quad*4+r, col=lm.
// ---------------------------------------------------------------------------
__constant__ int c_starts[6] = {0, 50, 67, 84, 101, 151};

__global__ __launch_bounds__(256)
void attn_kernel(ushort_t* __restrict__ qkv)
{
    // wave-private LDS; row stride 72 elems = 144 B (16B-aligned, <=2-way banks)
    alignas(16) __shared__ ushort_t Vt[4][32 * 72];  // V^T: [dh][key]
    alignas(16) __shared__ ushort_t Ps[4][16 * 72];  // P strip: [row][key]

    const int b    = blockIdx.x / 5;
    const int blk  = blockIdx.x % 5;
    const int a0   = c_starts[blk];
    const int n    = c_starts[blk + 1] - a0;
    const int wave = threadIdx.x >> 6;
    const int lane = threadIdx.x & 63;
    const int lm   = lane & 15;
    const int quad = lane >> 4;
    const float scale = 0.17677669529663687f;  // 1/sqrt(32)

    const size_t rowbase = (size_t)b * L_ + a0;

    for (int hi = 0; hi < 2; ++hi) {
        const int h = wave + hi * 4;
        const int hoff = h * 32;

        // ---- stage V^T into LDS (zero-pad keys >= n) ----
#pragma unroll
        for (int it = 0; it < 4; ++it) {
            int gidx = it * 64 + lane;
            int c    = gidx >> 2;          // key index 0..63
            int dcc  = (gidx & 3) * 8;     // dh chunk
            us8 v = *(const us8*)(qkv + (rowbase + c) * 768 + 512 + hoff + dcc);
            if (c >= n) v = (us8){0,0,0,0,0,0,0,0};
#pragma unroll
            for (int j = 0; j < 8; ++j)
                Vt[wave][(dcc + j) * 72 + c] = v[j];
        }

        // ---- K B-frags direct from global (keys >= n masked later) ----
        bf16x8 kb[4];
#pragma unroll
        for (int j = 0; j < 4; ++j)
            kb[j] = *(const bf16x8*)(qkv + (rowbase + 16 * j + lm) * 768 + 256 + hoff + quad * 8);

        // ---- V B-frags from LDS (in-wave ordering: compiler waits lgkmcnt) ----
        bf16x8 vb[2][2];
#pragma unroll
        for (int t = 0; t < 2; ++t)
#pragma unroll
            for (int kc = 0; kc < 2; ++kc)
                vb[t][kc] = *(const bf16x8*)&Vt[wave][(16 * t + lm) * 72 + kc * 32 + quad * 8];

        // ---- per 16-row query strip ----
        for (int i = 0; i < 4 && 16 * i < n; ++i) {
            bf16x8 qa = *(const bf16x8*)(qkv + (rowbase + 16 * i + lm) * 768 + hoff + quad * 8);

            f32x4 s[4];
#pragma unroll
            for (int j = 0; j < 4; ++j)
                s[j] = __builtin_amdgcn_mfma_f32_16x16x32_bf16(
                    qa, kb[j], (f32x4){0.f, 0.f, 0.f, 0.f}, 0, 0, 0);

            // scale + column mask
#pragma unroll
            for (int j = 0; j < 4; ++j) {
                bool valid = (16 * j + lm) < n;
#pragma unroll
                for (int r = 0; r < 4; ++r)
                    s[j][r] = valid ? s[j][r] * scale : -1e30f;
            }

            // row softmax (rows live in 16-lane groups sharing quad)
            float inv[4];
#pragma unroll
            for (int r = 0; r < 4; ++r) {
                float mx = fmaxf(fmaxf(s[0][r], s[1][r]), fmaxf(s[2][r], s[3][r]));
#pragma unroll
                for (int o2 = 1; o2 < 16; o2 <<= 1) mx = fmaxf(mx, __shfl_xor(mx, o2, 64));
                float sum = 0.f;
#pragma unroll
                for (int j = 0; j < 4; ++j) {
                    float ev = __expf(s[j][r] - mx);
                    s[j][r] = ev;
                    sum += ev;
                }
#pragma unroll
                for (int o2 = 1; o2 < 16; o2 <<= 1) sum += __shfl_xor(sum, o2, 64);
                inv[r] = 1.0f / sum;
            }

            // P strip: C-layout -> LDS (A-operand layout round-trip)
#pragma unroll
            for (int j = 0; j < 4; ++j)
#pragma unroll
                for (int r = 0; r < 4; ++r)
                    Ps[wave][(quad * 4 + r) * 72 + 16 * j + lm] = f2bf(s[j][r]);

            bf16x8 pa0 = *(const bf16x8*)&Ps[wave][lm * 72 + quad * 8];
            bf16x8 pa1 = *(const bf16x8*)&Ps[wave][lm * 72 + 32 + quad * 8];

            f32x4 o[2];
#pragma unroll
            for (int t = 0; t < 2; ++t) {
                o[t] = __builtin_amdgcn_mfma_f32_16x16x32_bf16(
                    pa0, vb[t][0], (f32x4){0.f, 0.f, 0.f, 0.f}, 0, 0, 0);
                o[t] = __builtin_amdgcn_mfma_f32_16x16x32_bf16(
                    pa1, vb[t][1], o[t], 0, 0, 0);
            }

            // write ctx over q columns (rows < n only)
#pragma unroll
            for (int r = 0; r < 4; ++r) {
                int m = 16 * i + quad * 4 + r;
                if (m < n) {
#pragma unroll
                    for (int t = 0; t < 2; ++t)
                        qkv[(rowbase + m) * 768 + hoff + 16 * t + lm] =
                            f2bf(o[t][r] * inv[r]);
                }
            }
        }
    }
}

// ---------------------------------------------------------------------------
// LayerNorm over pre-summed x_f32 (residual adds fused into GEMM epilogues).
// Writes post-LN fp32 stream + bf16 copy (or final fp32 output).
// ---------------------------------------------------------------------------
__global__ __launch_bounds__(256)
void ln_kernel(float* __restrict__ xf, const ushort_t* __restrict__ s,
               const ushort_t* __restrict__ b, ushort_t* __restrict__ xb_out,
               float* __restrict__ f32_dst, const int* __restrict__ flag,
               int is_final)
{
    const int wave = threadIdx.x >> 6;
    const int lane = threadIdx.x & 63;
    const int row  = blockIdx.x * 4 + wave;
    const size_t off = (size_t)row * D_ + lane * 4;

    float4 xv = *(const float4*)(xf + off);
    float v0 = xv.x, v1 = xv.y, v2 = xv.z, v3 = xv.w;

    float sum = v0 + v1 + v2 + v3;
#pragma unroll
    for (int o2 = 32; o2 > 0; o2 >>= 1) sum += __shfl_xor(sum, o2, 64);
    float mu = sum * (1.f / 256.f);

    float d0 = v0 - mu, d1 = v1 - mu, d2 = v2 - mu, d3 = v3 - mu;
    float ss = d0 * d0 + d1 * d1 + d2 * d2 + d3 * d3;
#pragma unroll
    for (int o2 = 32; o2 > 0; o2 >>= 1) ss += __shfl_xor(ss, o2, 64);
    float rstd = rsqrtf(ss * (1.f / 256.f) + 1e-5f);

    int c = lane * 4;
    float y0 = d0 * rstd * bf2f(s[c + 0]) + bf2f(b[c + 0]);
    float y1 = d1 * rstd * bf2f(s[c + 1]) + bf2f(b[c + 1]);
    float y2 = d2 * rstd * bf2f(s[c + 2]) + bf2f(b[c + 2]);
    float y3 = d3 * rstd * bf2f(s[c + 3]) + bf2f(b[c + 3]);

    *(float4*)(xf + off) = make_float4(y0, y1, y2, y3);
    if (is_final && *flag) {
        *(float4*)(f32_dst + off) = make_float4(y0, y1, y2, y3);
    } else {
        ushort4 uv;
        uv.x = f2bf(y0); uv.y = f2bf(y1); uv.z = f2bf(y2); uv.w = f2bf(y3);
        *(ushort4*)(xb_out + off) = uv;
    }
}

// ---------------------------------------------------------------------------
// Workspace: x_f32 39.58MB | U 59.38MB | Wbf 15.78MB | flag  = ~114.8MB
// (134.6MB passed last round; 198MB corrupted). x_b bf16 residual copy lives
// in d_out; final LN overwrites d_out with the real answer per dtype flag.
// ---------------------------------------------------------------------------
extern "C" void kernel_launch(void* const* d_in, const int* in_sizes, int n_in,
                              void* d_out, int out_size, void* d_ws, size_t ws_size,
                              hipStream_t stream)
{
    char* ws = (char*)d_ws;
    size_t o = 0;
    float*    x_f32 = (float*)(ws + o);    o += (size_t)M_ * D_ * 4;
    ushort_t* U     = (ushort_t*)(ws + o); o += (size_t)M_ * 768 * 2;
    ushort_t* Wbf   = (ushort_t*)(ws + o); o += (size_t)WTOT * 2;
    int*      flag  = (int*)(ws + o);      o += 256;
    ushort_t* x_b   = (ushort_t*)d_out;
    (void)ws_size; (void)in_sizes; (void)n_in; (void)out_size;

    detect_kernel<<<1, 256, 0, stream>>>((const unsigned int*)d_in[0], flag);

    WPtrs wp;
    for (int a = 0; a < 12; ++a) wp.p[a] = d_in[a + 1];
    cvt_all_kernel<<<(WTOT + 255) / 256, 256, 0, stream>>>(wp, flag, Wbf);

    // packed bf16 weight pointers (element offsets = cumulative sizes)
    const ushort_t* qkv_w = Wbf + 0;
    const ushort_t* qkv_b = Wbf + 1179648;
    const ushort_t* out_w = Wbf + 1184256;
    const ushort_t* out_b = Wbf + 1577472;
    const ushort_t* ff1_w = Wbf + 1579008;
    const ushort_t* ff1_b = Wbf + 4724736;
    const ushort_t* ff2_w = Wbf + 4737024;
    const ushort_t* ff2_b = Wbf + 7882752;
    const ushort_t* ln1_s = Wbf + 7884288;
    const ushort_t* ln1_b = Wbf + 7885824;
    const ushort_t* ln2_s = Wbf + 7887360;
    const ushort_t* ln2_b = Wbf + 7888896;

    cvt_src_kernel<<<(M_ * D_) / 256, 256, 0, stream>>>(d_in[0], flag, x_f32, x_b);

    const int chunk_tiles[4] = {76, 76, 75, 75};

    for (int i = 0; i < NL_; ++i) {
        // QKV projection -> U [M,768] bf16
        gemm_bt<<<dim3(6, M_ / 128), 256, 0, stream>>>(
            x_b, qkv_w + (size_t)i * 768 * D_, qkv_b + (size_t)i * 768, U,
            768, D_, D_, 0);
        // MFMA block-diagonal attention; ctx overwrites q columns of U
        attn_kernel<<<B_ * 5, 256, 0, stream>>>(U);
        // out projection: x_f32 += ctx @ out_w^T + out_b   (residual fused)
        gemm_bt<<<dim3(2, M_ / 128), 256, 0, stream>>>(
            U, out_w + (size_t)i * D_ * D_, out_b + (size_t)i * D_, x_f32,
            256, D_, 768, 2);
        // x = LN1(x)
        ln_kernel<<<M_ / 4, 256, 0, stream>>>(
            x_f32, ln1_s + (size_t)i * D_, ln1_b + (size_t)i * D_,
            x_b, nullptr, flag, 0);
        // FF in 4 M-chunks through U; FF2 fuses residual add into x_f32
        int t0 = 0;
        for (int c = 0; c < 4; ++c) {
            const int t = chunk_tiles[c];
            const size_t r0 = (size_t)t0 * 128;
            gemm_bt<<<dim3(16, t), 256, 0, stream>>>(
                x_b + r0 * D_, ff1_w + (size_t)i * FF_ * D_,
                ff1_b + (size_t)i * FF_, U, FF_, D_, D_, 1);
            gemm_bt<<<dim3(2, t), 256, 0, stream>>>(
                U, ff2_w + (size_t)i * D_ * FF_, ff2_b + (size_t)i * D_,
                x_f32 + r0 * D_, D_, FF_, FF_, 2);
            t0 += t;
        }
        // x = LN2(x); final layer writes d_out in the right dtype
        ln_kernel<<<M_ / 4, 256, 0, stream>>>(
            x_f32, ln2_s + (size_t)i * D_, ln2_b + (size_t)i * D_,
            x_b, (float*)d_out, flag, (i == NL_ - 1) ? 1 : 0);
    }
}